// Round 1
// baseline (711.676 us; speedup 1.0000x reference)
//
#include <hip/hip_runtime.h>

#define BB 500000
#define NN 256
#define AA 64
#define HH 100

typedef short short8 __attribute__((ext_vector_type(8)));
typedef float float4v __attribute__((ext_vector_type(4)));

#define MFMA16(a, b, c) __builtin_amdgcn_mfma_f32_16x16x32_bf16((a), (b), (c), 0, 0, 0)

__device__ __forceinline__ short f2bf(float f) {
    unsigned u = __builtin_bit_cast(unsigned, f);
    u = (u + 0x7fffu + ((u >> 16) & 1u)) >> 16;   // RNE to bf16
    return (short)u;
}

// ---- LDS layout (bytes) ----
// w1T  : short[112][72]   (gate-folded W1^T, k-pad 64->72, 16B-aligned rows)
// w2T  : short[112][136]  (W2^T, k-pad 128->136)
// w3T  : short[112][136]
// b1p/b2p/b3p : float[112] (bias, zero-padded)
// gate : float[64]
// X0   : 4 waves x short[16][72]
// X1,X2: 4 waves x short[16][136]
#define OFF_W1T   0
#define OFF_W2T   16128
#define OFF_W3T   46592
#define OFF_B1    77056
#define OFF_B2    77504
#define OFF_B3    77952
#define OFF_GATE  78400
#define OFF_X0    78656
#define OFF_X1    87872
#define OFF_X2    105280
#define LDS_TOTAL 122688

#define NTILES ((BB + 63) / 64)   // 7813

__global__ void __launch_bounds__(256, 1)
nodal_mlp(const float* __restrict__ data, const float* __restrict__ weights,
          const float* __restrict__ W1, const float* __restrict__ b1,
          const float* __restrict__ W2, const float* __restrict__ b2,
          const float* __restrict__ W3, const float* __restrict__ b3,
          const float* __restrict__ W4, const float* __restrict__ b4,
          const int* __restrict__ didx, const int* __restrict__ edir,
          const int* __restrict__ widx, float* __restrict__ out)
{
    extern __shared__ char smem[];
    short* w1T  = (short*)(smem + OFF_W1T);
    short* w2T  = (short*)(smem + OFF_W2T);
    short* w3T  = (short*)(smem + OFF_W3T);
    float* b1p  = (float*)(smem + OFF_B1);
    float* b2p  = (float*)(smem + OFF_B2);
    float* b3p  = (float*)(smem + OFF_B3);
    float* gate = (float*)(smem + OFF_GATE);

    const int tid  = threadIdx.x;
    const int wave = tid >> 6;
    const int lane = tid & 63;
    const int m    = lane & 15;   // MFMA row (A) / col (C)
    const int quad = lane >> 4;   // MFMA k-group / C row-group

    short* X0w = (short*)(smem + OFF_X0) + wave * (16 * 72);
    short* X1w = (short*)(smem + OFF_X1) + wave * (16 * 136);
    short* X2w = (short*)(smem + OFF_X2) + wave * (16 * 136);

    // ---- one-time staging ----
    if (tid < AA)
        gate[tid] = fmaxf(weights[widx[tid]] * (float)edir[tid], 0.f);
    if (tid < 112) {
        b1p[tid] = (tid < HH) ? b1[tid] : 0.f;
        b2p[tid] = (tid < HH) ? b2[tid] : 0.f;
        b3p[tid] = (tid < HH) ? b3[tid] : 0.f;
    }
    for (int i = tid; i < 112 * 72; i += 256) w1T[i] = 0;
    for (int i = tid; i < 112 * 136; i += 256) { w2T[i] = 0; w3T[i] = 0; }
    // zero X1/X2 pad cols k in [112,128) (read by next layer's K loop, never rewritten)
    for (int i = lane; i < 16 * 16; i += 64) {
        int r = i >> 4, k = 112 + (i & 15);
        X1w[r * 136 + k] = 0;
        X2w[r * 136 + k] = 0;
    }
    __syncthreads();
    for (int j = tid; j < AA * HH; j += 256) {        // W1 coalesced read, gate folded
        int k = j / HH, n = j - k * HH;               // W1[k][n]
        w1T[n * 72 + k] = f2bf(gate[k] * W1[j]);
    }
    for (int j = tid; j < HH * HH; j += 256) {        // W2/W3 coalesced read
        int k = j / HH, n = j - k * HH;
        w2T[n * 136 + k] = f2bf(W2[j]);
        w3T[n * 136 + k] = f2bf(W3[j]);
    }
    __syncthreads();
    // no further barriers: activations are wave-private, weights read-only

    // W4 as a register B-fragment (only column n==0 non-zero)
    short8 w4f[4];
    #pragma unroll
    for (int ks = 0; ks < 4; ++ks) {
        #pragma unroll
        for (int j = 0; j < 8; ++j) {
            int k = ks * 32 + quad * 8 + j;
            w4f[ks][j] = (m == 0 && k < HH) ? f2bf(W4[k]) : (short)0;
        }
    }
    const float b4v   = b4[0];
    const int  colOff = didx[lane];   // lane == edge index (A == 64)

    float pf[16];
    int t = (int)blockIdx.x;
    {   // prefetch first tile
        int r0 = t * 64 + wave * 16;
        const float* p = data + (size_t)colOff;
        if (r0 + 16 <= BB) {
            const float* q = p + (size_t)r0 * NN;
            #pragma unroll
            for (int r = 0; r < 16; ++r) pf[r] = q[r * NN];
        } else {
            #pragma unroll
            for (int r = 0; r < 16; ++r) {
                int row = r0 + r; row = row < BB ? row : BB - 1;
                pf[r] = p[(size_t)row * NN];
            }
        }
    }

    for (; t < NTILES; t += gridDim.x) {
        const int r0 = t * 64 + wave * 16;

        // stage current tile's gathered X0 (bf16, A-layout-friendly row-major)
        #pragma unroll
        for (int r = 0; r < 16; ++r)
            X0w[r * 72 + lane] = f2bf(pf[r]);

        // software-pipeline: issue next tile's scattered loads now
        int tn = t + (int)gridDim.x;
        if (tn < NTILES) {
            int r0n = tn * 64 + wave * 16;
            const float* p = data + (size_t)colOff;
            if (r0n + 16 <= BB) {
                const float* q = p + (size_t)r0n * NN;
                #pragma unroll
                for (int r = 0; r < 16; ++r) pf[r] = q[r * NN];
            } else {
                #pragma unroll
                for (int r = 0; r < 16; ++r) {
                    int row = r0n + r; row = row < BB ? row : BB - 1;
                    pf[r] = p[(size_t)row * NN];
                }
            }
        }

        // ---- layer 1: X0[16x64] @ W1g[64x112] -> X1 (relu) ----
        {
            short8 a0 = *(const short8*)(X0w + m * 72 + quad * 8);
            short8 a1 = *(const short8*)(X0w + m * 72 + 32 + quad * 8);
            #pragma unroll
            for (int nt = 0; nt < 7; ++nt) {
                const short* wp = w1T + (nt * 16 + m) * 72 + quad * 8;
                float4v c = {0.f, 0.f, 0.f, 0.f};
                c = MFMA16(a0, *(const short8*)(wp), c);
                c = MFMA16(a1, *(const short8*)(wp + 32), c);
                float bias = b1p[nt * 16 + m];
                #pragma unroll
                for (int i = 0; i < 4; ++i)
                    X1w[(quad * 4 + i) * 136 + nt * 16 + m] =
                        f2bf(fmaxf(c[i] + bias, 0.f));
            }
        }

        // ---- layer 2: X1 @ W2 -> X2 ; layer 3: X2 @ W3 -> X1 ----
        #pragma unroll
        for (int L = 0; L < 2; ++L) {
            const short* Xin  = L ? X2w : X1w;
            short*       Xout = L ? X1w : X2w;
            const short* wT   = L ? w3T : w2T;
            const float* bp   = L ? b3p : b2p;
            short8 a[4];
            #pragma unroll
            for (int ks = 0; ks < 4; ++ks)
                a[ks] = *(const short8*)(Xin + m * 136 + ks * 32 + quad * 8);
            #pragma unroll
            for (int nt = 0; nt < 7; ++nt) {
                float4v c = {0.f, 0.f, 0.f, 0.f};
                #pragma unroll
                for (int ks = 0; ks < 4; ++ks)
                    c = MFMA16(a[ks],
                               *(const short8*)(wT + (nt * 16 + m) * 136 + ks * 32 + quad * 8),
                               c);
                float bias = bp[nt * 16 + m];
                #pragma unroll
                for (int i = 0; i < 4; ++i)
                    Xout[(quad * 4 + i) * 136 + nt * 16 + m] =
                        f2bf(fmaxf(c[i] + bias, 0.f));
            }
        }

        // ---- layer 4: X3(=X1w)[16x100] . W4 -> out ----
        {
            float4v c = {0.f, 0.f, 0.f, 0.f};
            #pragma unroll
            for (int ks = 0; ks < 4; ++ks) {
                short8 a = *(const short8*)(X1w + m * 136 + ks * 32 + quad * 8);
                c = MFMA16(a, w4f[ks], c);
            }
            if (m == 0) {   // C col 0 lives in lanes 0,16,32,48; rows quad*4+i
                #pragma unroll
                for (int i = 0; i < 4; ++i) {
                    int row = r0 + quad * 4 + i;
                    if (row < BB) out[row] = c[i] + b4v;
                }
            }
        }
    }
}

extern "C" void kernel_launch(void* const* d_in, const int* in_sizes, int n_in,
                              void* d_out, int out_size, void* d_ws, size_t ws_size,
                              hipStream_t stream) {
    (void)in_sizes; (void)n_in; (void)d_ws; (void)ws_size; (void)out_size;
    const float* data    = (const float*)d_in[0];
    const float* weights = (const float*)d_in[1];
    const float* W1      = (const float*)d_in[2];
    const float* b1      = (const float*)d_in[3];
    const float* W2      = (const float*)d_in[4];
    const float* b2      = (const float*)d_in[5];
    const float* W3      = (const float*)d_in[6];
    const float* b3      = (const float*)d_in[7];
    const float* W4      = (const float*)d_in[8];
    const float* b4      = (const float*)d_in[9];
    const int*   didx    = (const int*)d_in[10];
    const int*   edir    = (const int*)d_in[11];
    const int*   widx    = (const int*)d_in[12];
    float* out = (float*)d_out;

    hipFuncSetAttribute((const void*)nodal_mlp,
                        hipFuncAttributeMaxDynamicSharedMemorySize, LDS_TOTAL);
    nodal_mlp<<<256, 256, LDS_TOTAL, stream>>>(
        data, weights, W1, b1, W2, b2, W3, b3, W4, b4, didx, edir, widx, out);
}

// Round 2
// 697.421 us; speedup vs baseline: 1.0204x; 1.0204x over previous
//
#include <hip/hip_runtime.h>

#define BB 500000
#define NN 256
#define AA 64
#define HH 100

typedef short short8 __attribute__((ext_vector_type(8)));
typedef float float4v __attribute__((ext_vector_type(4)));

#define MFMA16(a, b, c) __builtin_amdgcn_mfma_f32_16x16x32_bf16((a), (b), (c), 0, 0, 0)

__device__ __forceinline__ short f2bf(float f) {
    unsigned u = __builtin_bit_cast(unsigned, f);
    u = (u + 0x7fffu + ((u >> 16) & 1u)) >> 16;   // RNE to bf16
    return (short)u;
}

// ---- LDS layout (bytes) ----
// w1T  : short[112][72]   (gate-folded W1^T, k-pad 64->72; 72*2=144B stride -> 2-way banks, free)
// w2T  : short[112][136]  (W2^T, k-pad 100->128, stride 136 -> 2-way banks)
// w3T  : short[112][136]
// b1p/b2p/b3p : float[112]
// gate : float[64]
// X    : 8 waves x short[32][136]  (single buffer reused across all 4 layers)
#define OFF_W1T   0
#define OFF_W2T   16128
#define OFF_W3T   46592
#define OFF_B1    77056
#define OFF_B2    77504
#define OFF_B3    77952
#define OFF_GATE  78400
#define OFF_X     78656
#define LDS_TOTAL 148288   // 144.8 KiB -> 1 block/CU, 8 waves = 2 waves/SIMD

#define ROWS_PER_TILE 256  // 8 waves x 32 rows
#define NTILES ((BB + ROWS_PER_TILE - 1) / ROWS_PER_TILE)   // 1954

__global__ void __launch_bounds__(512, 2)
nodal_mlp(const float* __restrict__ data, const float* __restrict__ weights,
          const float* __restrict__ W1, const float* __restrict__ b1,
          const float* __restrict__ W2, const float* __restrict__ b2,
          const float* __restrict__ W3, const float* __restrict__ b3,
          const float* __restrict__ W4, const float* __restrict__ b4,
          const int* __restrict__ didx, const int* __restrict__ edir,
          const int* __restrict__ widx, float* __restrict__ out)
{
    extern __shared__ char smem[];
    short* w1T  = (short*)(smem + OFF_W1T);
    short* w2T  = (short*)(smem + OFF_W2T);
    short* w3T  = (short*)(smem + OFF_W3T);
    float* b1p  = (float*)(smem + OFF_B1);
    float* b2p  = (float*)(smem + OFF_B2);
    float* b3p  = (float*)(smem + OFF_B3);
    float* gate = (float*)(smem + OFF_GATE);

    const int tid  = threadIdx.x;
    const int wave = tid >> 6;    // 0..7
    const int lane = tid & 63;
    const int m    = lane & 15;   // MFMA A-row / C-col
    const int quad = lane >> 4;   // MFMA k-group / C row-group

    short* Xw = (short*)(smem + OFF_X) + wave * (32 * 136);

    // ---- one-time staging ----
    if (tid < AA)
        gate[tid] = fmaxf(weights[widx[tid]] * (float)edir[tid], 0.f);
    if (tid < 112) {
        b1p[tid] = (tid < HH) ? b1[tid] : 0.f;
        b2p[tid] = (tid < HH) ? b2[tid] : 0.f;
        b3p[tid] = (tid < HH) ? b3[tid] : 0.f;
    }
    for (int i = tid; i < 112 * 72; i += 512) w1T[i] = 0;
    for (int i = tid; i < 112 * 136; i += 512) { w2T[i] = 0; w3T[i] = 0; }
    // zero X pad cols k in [112,128): read by L2/L3 K-loops, never rewritten
    for (int i = lane; i < 32 * 16; i += 64) {
        int r = i >> 4, k = 112 + (i & 15);
        Xw[r * 136 + k] = 0;
    }
    __syncthreads();
    for (int j = tid; j < AA * HH; j += 512) {        // gate-folded W1^T
        int k = j / HH, n = j - k * HH;
        w1T[n * 72 + k] = f2bf(gate[k] * W1[j]);
    }
    for (int j = tid; j < HH * HH; j += 512) {
        int k = j / HH, n = j - k * HH;
        w2T[n * 136 + k] = f2bf(W2[j]);
        w3T[n * 136 + k] = f2bf(W3[j]);
    }
    __syncthreads();
    // no barriers in main loop: X is wave-private, weights read-only

    // W4 as register B-fragments (only column n==0 non-zero)
    short8 w4f[4];
    #pragma unroll
    for (int ks = 0; ks < 4; ++ks) {
        #pragma unroll
        for (int j = 0; j < 8; ++j) {
            int k = ks * 32 + quad * 8 + j;
            w4f[ks][j] = (m == 0 && k < HH) ? f2bf(W4[k]) : (short)0;
        }
    }
    const float b4v   = b4[0];
    const int  colOff = didx[lane];   // lane == edge index (A == 64)

    float pf[32];
    int t = (int)blockIdx.x;
    {   // prefetch first tile: 32 rows, scattered per-lane column
        int r0 = t * ROWS_PER_TILE + wave * 32;
        const float* p = data + (size_t)colOff;
        if (r0 + 32 <= BB) {
            const float* q = p + (size_t)r0 * NN;
            #pragma unroll
            for (int r = 0; r < 32; ++r) pf[r] = q[r * NN];
        } else {
            #pragma unroll
            for (int r = 0; r < 32; ++r) {
                int row = r0 + r; row = row < BB ? row : BB - 1;
                pf[r] = p[(size_t)row * NN];
            }
        }
    }

    for (; t < NTILES; t += gridDim.x) {
        const int r0 = t * ROWS_PER_TILE + wave * 32;

        // stage gathered X0 (bf16) into cols 0..63 of the wave buffer
        #pragma unroll
        for (int r = 0; r < 32; ++r)
            Xw[r * 136 + lane] = f2bf(pf[r]);

        // software-pipeline: issue next tile's scattered loads now
        {
            int tn = t + (int)gridDim.x;
            if (tn < NTILES) {
                int r0n = tn * ROWS_PER_TILE + wave * 32;
                const float* p = data + (size_t)colOff;
                if (r0n + 32 <= BB) {
                    const float* q = p + (size_t)r0n * NN;
                    #pragma unroll
                    for (int r = 0; r < 32; ++r) pf[r] = q[r * NN];
                } else {
                    #pragma unroll
                    for (int r = 0; r < 32; ++r) {
                        int row = r0n + r; row = row < BB ? row : BB - 1;
                        pf[r] = p[(size_t)row * NN];
                    }
                }
            }
        }

        // ---- layer 1: X[32x64] @ W1g[64x112] -> X (relu), 2 subtiles share W reads
        {
            short8 a1[2][2];
            #pragma unroll
            for (int sub = 0; sub < 2; ++sub)
                #pragma unroll
                for (int ks = 0; ks < 2; ++ks)
                    a1[sub][ks] = *(const short8*)(Xw + (sub * 16 + m) * 136 + ks * 32 + quad * 8);
            #pragma unroll
            for (int nt = 0; nt < 7; ++nt) {
                const short* wp = w1T + (nt * 16 + m) * 72 + quad * 8;
                short8 w0 = *(const short8*)(wp);
                short8 w1v = *(const short8*)(wp + 32);
                float bias = b1p[nt * 16 + m];
                #pragma unroll
                for (int sub = 0; sub < 2; ++sub) {
                    float4v c = {0.f, 0.f, 0.f, 0.f};
                    c = MFMA16(a1[sub][0], w0, c);
                    c = MFMA16(a1[sub][1], w1v, c);
                    #pragma unroll
                    for (int i = 0; i < 4; ++i)
                        Xw[(sub * 16 + quad * 4 + i) * 136 + nt * 16 + m] =
                            f2bf(fmaxf(c[i] + bias, 0.f));
                }
            }
        }

        // ---- layers 2 & 3: X @ W -> X (relu), in-place, W reads shared by 2 subtiles
        #pragma unroll
        for (int L = 0; L < 2; ++L) {
            const short* wT = L ? w3T : w2T;
            const float* bp = L ? b3p : b2p;
            short8 a[2][4];
            #pragma unroll
            for (int sub = 0; sub < 2; ++sub)
                #pragma unroll
                for (int ks = 0; ks < 4; ++ks)
                    a[sub][ks] = *(const short8*)(Xw + (sub * 16 + m) * 136 + ks * 32 + quad * 8);
            #pragma unroll
            for (int nt = 0; nt < 7; ++nt) {
                const short* wp = wT + (nt * 16 + m) * 136 + quad * 8;
                short8 wf[4];
                #pragma unroll
                for (int ks = 0; ks < 4; ++ks)
                    wf[ks] = *(const short8*)(wp + ks * 32);
                float bias = bp[nt * 16 + m];
                #pragma unroll
                for (int sub = 0; sub < 2; ++sub) {
                    float4v c = {0.f, 0.f, 0.f, 0.f};
                    #pragma unroll
                    for (int ks = 0; ks < 4; ++ks)
                        c = MFMA16(a[sub][ks], wf[ks], c);
                    #pragma unroll
                    for (int i = 0; i < 4; ++i)
                        Xw[(sub * 16 + quad * 4 + i) * 136 + nt * 16 + m] =
                            f2bf(fmaxf(c[i] + bias, 0.f));
                }
            }
        }

        // ---- layer 4: X[32x100] . W4 -> out ----
        #pragma unroll
        for (int sub = 0; sub < 2; ++sub) {
            float4v c = {0.f, 0.f, 0.f, 0.f};
            #pragma unroll
            for (int ks = 0; ks < 4; ++ks) {
                short8 a = *(const short8*)(Xw + (sub * 16 + m) * 136 + ks * 32 + quad * 8);
                c = MFMA16(a, w4f[ks], c);
            }
            if (m == 0) {   // C col 0 lives in lanes {0,16,32,48}; rows quad*4+i
                #pragma unroll
                for (int i = 0; i < 4; ++i) {
                    int row = r0 + sub * 16 + quad * 4 + i;
                    if (row < BB) out[row] = c[i] + b4v;
                }
            }
        }
    }
}

extern "C" void kernel_launch(void* const* d_in, const int* in_sizes, int n_in,
                              void* d_out, int out_size, void* d_ws, size_t ws_size,
                              hipStream_t stream) {
    (void)in_sizes; (void)n_in; (void)d_ws; (void)ws_size; (void)out_size;
    const float* data    = (const float*)d_in[0];
    const float* weights = (const float*)d_in[1];
    const float* W1      = (const float*)d_in[2];
    const float* b1      = (const float*)d_in[3];
    const float* W2      = (const float*)d_in[4];
    const float* b2      = (const float*)d_in[5];
    const float* W3      = (const float*)d_in[6];
    const float* b3      = (const float*)d_in[7];
    const float* W4      = (const float*)d_in[8];
    const float* b4      = (const float*)d_in[9];
    const int*   didx    = (const int*)d_in[10];
    const int*   edir    = (const int*)d_in[11];
    const int*   widx    = (const int*)d_in[12];
    float* out = (float*)d_out;

    hipFuncSetAttribute((const void*)nodal_mlp,
                        hipFuncAttributeMaxDynamicSharedMemorySize, LDS_TOTAL);
    nodal_mlp<<<256, 512, LDS_TOTAL, stream>>>(
        data, weights, W1, b1, W2, b2, W3, b3, W4, b4, didx, edir, widx, out);
}